// Round 1
// baseline (55.771 us; speedup 1.0000x reference)
//
#include <hip/hip_runtime.h>

// WOMD post-processing: one 64-thread block per (scene, agent).
// Inputs (float32): ag_type (64,64,3) one-hot, trajs (64,32,64,80,3), scores (64,32,64).
// Output: concat[ trajs_out (64,64,6,16,3), scores_out (64,64,6) ] float32.

#define NSC 64
#define NAG 64
#define NJF 32
#define NSTEP 80
#define KP 6
#define TOUT 16

__global__ __launch_bounds__(64)
void womd_pp_kernel(const float* __restrict__ ag_type,
                    const float* __restrict__ trajs,
                    const float* __restrict__ scores,
                    float* __restrict__ out)
{
    const int b = blockIdx.x;          // 0..4095
    const int s = b >> 6;              // scene
    const int a = b & 63;              // agent
    const int tid = threadIdx.x;

    __shared__ float raw[NJF];         // raw scores (pre-softmax)
    __shared__ float sm[NJF];          // softmaxed scores
    __shared__ float ex[NJF][2];       // endpoints (t=79, xy)
    __shared__ unsigned wmask[NJF];    // within bitmask rows (32x32)
    __shared__ int sel[KP];            // selected mode indices
    __shared__ float outsc[KP];        // final scores

    // threshold = ag_type @ [2.5, 1.0, 2.0]  (one-hot -> picks one)
    const float* at = ag_type + (size_t)(s * NAG + a) * 3;
    const float thresh = at[0] * 2.5f + at[1] * 1.0f + at[2] * 2.0f;

    if (tid < NJF) {
        // scores input layout: (n_sc, n_jf, n_ag); after swapaxes ref uses [s, a, j]
        raw[tid] = scores[((size_t)s * NJF + tid) * NAG + a];
        // endpoint: trajs_in[s, j, a, 79, 0:2]
        size_t off = (((size_t)(s * NJF + tid) * NAG + a) * NSTEP + (NSTEP - 1)) * 3;
        ex[tid][0] = trajs[off];
        ex[tid][1] = trajs[off + 1];
    }
    __syncthreads();

    if (tid < NJF) {
        // softmax over the 32 futures (redundant per-lane reduce; 32 elems, cheap)
        float mx = raw[0];
        for (int j = 1; j < NJF; ++j) mx = fmaxf(mx, raw[j]);
        float sum = 0.f;
        for (int j = 0; j < NJF; ++j) sum += expf(raw[j] - mx);
        sm[tid] = expf(raw[tid] - mx) / sum;

        // within row: dist(end[tid], end[j]) < thresh  (strict <, sqrt like jnp.linalg.norm)
        float x = ex[tid][0], y = ex[tid][1];
        unsigned m = 0;
        for (int j = 0; j < NJF; ++j) {
            float dx = x - ex[j][0], dy = y - ex[j][1];
            if (sqrtf(dx * dx + dy * dy) < thresh) m |= (1u << j);
        }
        wmask[tid] = m;
    }
    __syncthreads();

    if (tid == 0) {
        // ---- MTR NMS: 6 sequential argmax picks ----
        float ls[NJF];
        for (int j = 0; j < NJF; ++j) ls[j] = sm[j];
        for (int k = 0; k < KP; ++k) {
            int best = 0; float bv = ls[0];
            for (int j = 1; j < NJF; ++j)
                if (ls[j] > bv) { bv = ls[j]; best = j; }   // strict >: first-max like jnp.argmax
            sel[k] = best;
            unsigned w = wmask[best];
            // sc *= within ? 0.01 : (0.99+0.01==1.0f); applies to ALL entries incl. past picks
            for (int j = 0; j < NJF; ++j)
                ls[j] *= ((w >> j) & 1u) ? 0.01f : 1.0f;
            ls[best] = -1.0f;
        }

        // scores_k from ORIGINAL softmax scores, normalized
        float sk[KP]; float ssum = 0.f;
        for (int k = 0; k < KP; ++k) { sk[k] = sm[sel[k]]; ssum += sk[k]; }
        for (int k = 0; k < KP; ++k) sk[k] /= ssum;

        // ---- second within (6x6) with MPA thresh (same values) ----
        bool w2[KP][KP];
        for (int i = 0; i < KP; ++i)
            for (int j = 0; j < KP; ++j) {
                float dx = ex[sel[i]][0] - ex[sel[j]][0];
                float dy = ex[sel[i]][1] - ex[sel[j]][1];
                w2[i][j] = sqrtf(dx * dx + dy * dy) < thresh;
            }

        // argsort(-sk), stable: descending, ties -> lower index first
        int order[KP]; bool used[KP] = {false, false, false, false, false, false};
        for (int t = 0; t < KP; ++t) {
            int best = -1; float bv = 0.f;
            for (int j = 0; j < KP; ++j)
                if (!used[j] && (best < 0 || sk[j] > bv)) { best = j; bv = sk[j]; }
            order[t] = best; used[best] = true;
        }

        // ---- MPA NMS scan (uses CURRENT sk values as it goes) ----
        for (int t = 0; t < KP; ++t) {
            int k = order[t];
            bool any = false;
            for (int j = 0; j < KP; ++j)
                if (w2[k][j] && sk[j] > sk[k]) any = true;
            if (any) sk[k] = 0.001f;
        }

        // normalize, then softmax(log p / 0.5) == p^2 / sum(p^2)
        float s2 = 0.f;
        for (int k = 0; k < KP; ++k) s2 += sk[k];
        for (int k = 0; k < KP; ++k) sk[k] /= s2;
        float q[KP]; float s3 = 0.f;
        for (int k = 0; k < KP; ++k) { q[k] = sk[k] * sk[k]; s3 += q[k]; }
        for (int k = 0; k < KP; ++k) outsc[k] = q[k] / s3;
    }
    __syncthreads();

    // ---- outputs ----
    const size_t SCBASE = (size_t)NSC * NAG * KP * TOUT * 3;   // 1,179,648
    if (tid < KP) out[SCBASE + (size_t)b * KP + tid] = outsc[tid];

    // trajs_out[s,a,m,t,c] = trajs_in[s, sel[m], a, 4+5t, c]
    for (int e = tid; e < KP * TOUT * 3; e += 64) {
        int m = e / 48;
        int r = e - m * 48;
        int t = r / 3;
        int c = r - t * 3;
        size_t src = (((size_t)(s * NJF + sel[m]) * NAG + a) * NSTEP + (4 + 5 * t)) * 3 + c;
        out[(size_t)b * (KP * TOUT * 3) + e] = trajs[src];
    }
}

extern "C" void kernel_launch(void* const* d_in, const int* in_sizes, int n_in,
                              void* d_out, int out_size, void* d_ws, size_t ws_size,
                              hipStream_t stream) {
    const float* ag_type = (const float*)d_in[0];
    const float* trajs   = (const float*)d_in[1];
    const float* scores  = (const float*)d_in[2];
    float* out = (float*)d_out;

    womd_pp_kernel<<<NSC * NAG, 64, 0, stream>>>(ag_type, trajs, scores, out);
}

// Round 2
// 33.228 us; speedup vs baseline: 1.6784x; 1.6784x over previous
//
#include <hip/hip_runtime.h>

// WOMD post-processing, v2: one 64-lane wave handles TWO (scene,agent) pairs
// (lanes 0-31 -> agent 2p, lanes 32-63 -> agent 2p+1). All reductions are
// width-32 shuffle butterflies; only the tiny 6x6 MPA tail is serial (runs
// concurrently on lanes 0 and 32). Trajectory gather loads are issued before
// the MPA tail so HBM latency overlaps the serial section.

#define NSC 64
#define NAG 64
#define NJF 32
#define NSTEP 80
#define KP 6
#define TOUT 16

struct F3 { float x, y, z; };

__global__ __launch_bounds__(64)
void womd_pp2(const float* __restrict__ ag_type,
              const float* __restrict__ trajs,
              const float* __restrict__ scores,
              float* __restrict__ out)
{
    const int tid  = threadIdx.x;
    const int half = tid >> 5;          // which agent of the pair
    const int hl   = tid & 31;          // lane within 32-group = mode index
    const int s    = blockIdx.x >> 5;   // scene
    const int p    = blockIdx.x & 31;   // agent-pair
    const int a    = p * 2 + half;      // agent

    __shared__ float exs[2][NJF][2];    // endpoints per half
    __shared__ float sms[2][NJF];       // softmax scores per half
    __shared__ int   selsh[2][KP];      // MTR picks per half

    // ---- loads (issued up front) ----
    float raw = scores[((size_t)s * NJF + hl) * NAG + a];
    size_t eoff = (((size_t)(s * NJF + hl) * NAG + a) * NSTEP + (NSTEP - 1)) * 3;
    float exx = trajs[eoff];
    float exy = trajs[eoff + 1];
    const float* at = ag_type + (size_t)(s * NAG + a) * 3;
    const float thresh = at[0] * 2.5f + at[1] * 1.0f + at[2] * 2.0f;

    exs[half][hl][0] = exx;
    exs[half][hl][1] = exy;

    // ---- softmax over 32 modes (width-32 butterfly, 1 expf/lane) ----
    float mx = raw;
    #pragma unroll
    for (int off = 16; off > 0; off >>= 1)
        mx = fmaxf(mx, __shfl_xor(mx, off, 32));
    float ev = expf(raw - mx);
    float sum = ev;
    #pragma unroll
    for (int off = 16; off > 0; off >>= 1)
        sum += __shfl_xor(sum, off, 32);
    float sm = ev / sum;
    sms[half][hl] = sm;

    __syncthreads();

    // ---- within bitmask: row hl (strict <, sqrt like jnp.linalg.norm) ----
    unsigned m = 0;
    #pragma unroll 8
    for (int j = 0; j < NJF; ++j) {
        float dx = exx - exs[half][j][0];
        float dy = exy - exs[half][j][1];
        if (sqrtf(dx * dx + dy * dy) < thresh) m |= (1u << j);
    }

    // ---- MTR NMS: 6 picks, wave-parallel ----
    float ls = sm;
    #pragma unroll
    for (int k = 0; k < KP; ++k) {
        // argmax with first-index tie-break (matches jnp.argmax)
        float v = ls; int idx = hl;
        #pragma unroll
        for (int off = 16; off > 0; off >>= 1) {
            float ov = __shfl_xor(v, off, 32);
            int   oi = __shfl_xor(idx, off, 32);
            if (ov > v || (ov == v && oi < idx)) { v = ov; idx = oi; }
        }
        unsigned wb = __shfl(m, idx, 32);          // within-row of the pick
        // sc *= within ? 0.01 : (0.99f+0.01f == 1.0f)
        ls *= ((wb >> hl) & 1u) ? 0.01f : 1.0f;
        if (hl == idx) ls = -1.0f;
        if (hl == 0) selsh[half][k] = idx;
    }
    __syncthreads();

    // ---- trajectory gather: issue loads NOW (overlap with MPA tail) ----
    // 96 points (6 modes x 16 steps) per agent, 3 per lane, 12B each.
    F3 pt[3];
    #pragma unroll
    for (int i = 0; i < 3; ++i) {
        int e  = hl + 32 * i;          // 0..95
        int mm = e >> 4;               // mode 0..5
        int t  = e & 15;               // step 0..15
        int sj = selsh[half][mm];
        size_t src = (((size_t)(s * NJF + sj) * NAG + a) * NSTEP + (4 + 5 * t)) * 3;
        pt[i] = *(const F3*)(trajs + src);
    }

    // ---- MPA tail: serial 6x6, lanes 0 and 32 concurrently ----
    if (hl == 0) {
        int   sel[KP];
        float sk[KP], sx[KP], sy[KP];
        float ssum = 0.f;
        #pragma unroll
        for (int k = 0; k < KP; ++k) {
            sel[k] = selsh[half][k];
            sk[k]  = sms[half][sel[k]];
            ssum  += sk[k];
            sx[k]  = exs[half][sel[k]][0];
            sy[k]  = exs[half][sel[k]][1];
        }
        #pragma unroll
        for (int k = 0; k < KP; ++k) sk[k] /= ssum;

        bool w2[KP][KP];
        #pragma unroll
        for (int i = 0; i < KP; ++i)
            #pragma unroll
            for (int j = 0; j < KP; ++j) {
                float dx = sx[i] - sx[j], dy = sy[i] - sy[j];
                w2[i][j] = sqrtf(dx * dx + dy * dy) < thresh;
            }

        // stable descending argsort (ties -> lower index), then MPA scan
        int order[KP]; bool used[KP] = {false,false,false,false,false,false};
        #pragma unroll
        for (int t = 0; t < KP; ++t) {
            int best = -1; float bv = 0.f;
            #pragma unroll
            for (int j = 0; j < KP; ++j)
                if (!used[j] && (best < 0 || sk[j] > bv)) { best = j; bv = sk[j]; }
            order[t] = best; used[best] = true;
        }
        #pragma unroll
        for (int t = 0; t < KP; ++t) {
            int k = order[t];
            bool any = false;
            #pragma unroll
            for (int j = 0; j < KP; ++j)
                if (w2[k][j] && sk[j] > sk[k]) any = true;
            if (any) sk[k] = 0.001f;
        }

        // normalize; softmax(log p / 0.5) == p^2 / sum(p^2)
        float s2 = 0.f;
        #pragma unroll
        for (int k = 0; k < KP; ++k) s2 += sk[k];
        #pragma unroll
        for (int k = 0; k < KP; ++k) sk[k] /= s2;
        float s3 = 0.f; float q[KP];
        #pragma unroll
        for (int k = 0; k < KP; ++k) { q[k] = sk[k] * sk[k]; s3 += q[k]; }

        const size_t SCBASE = (size_t)NSC * NAG * KP * TOUT * 3;
        size_t scb = SCBASE + ((size_t)s * NAG + a) * KP;
        #pragma unroll
        for (int k = 0; k < KP; ++k) out[scb + k] = q[k] / s3;
    }

    // ---- trajectory stores (loads已 in flight during the tail) ----
    size_t ob = ((size_t)s * NAG + a) * (KP * TOUT * 3);
    #pragma unroll
    for (int i = 0; i < 3; ++i) {
        int e = hl + 32 * i;
        *(F3*)(out + ob + (size_t)e * 3) = pt[i];
    }
}

extern "C" void kernel_launch(void* const* d_in, const int* in_sizes, int n_in,
                              void* d_out, int out_size, void* d_ws, size_t ws_size,
                              hipStream_t stream) {
    const float* ag_type = (const float*)d_in[0];
    const float* trajs   = (const float*)d_in[1];
    const float* scores  = (const float*)d_in[2];
    float* out = (float*)d_out;

    womd_pp2<<<NSC * (NAG / 2), 64, 0, stream>>>(ag_type, trajs, scores, out);
}